// Round 1
// baseline (669.214 us; speedup 1.0000x reference)
//
#include <hip/hip_runtime.h>
#include <hip/hip_bf16.h>
#include <cstdint>
#include <cstddef>

// Problem constants (BahdanauAttention): B=32, S=2048, d=512, M=512, K=2d=1024
#define B_   32
#define S_   2048
#define D_   512
#define K2D  1024
#define M_   512

// ws layout (float indices). Total need = 82528*4 + 1 MB = 1.32 MB.
// Round 3 proved ws >= 1.64 MB, so safe.
#define WS_SCORES 0            // [B][S] = 65536 floats
#define WS_WQ     65536        // [B][M] = 16384 floats
#define WS_FLAG   81920        // 1 int
#define WS_DENOM  81984        // 32 floats (softmax denominators, unnormalized)
#define WS_CNT    82016        // 512 ints  (per-(b,s-chunk) arrival counters)
#define WS_UAB16  82528        // 512*1024 bf16 = 1 MB (82528*4 % 16 == 0)

typedef __attribute__((ext_vector_type(8))) short bf16x8;   // 8 bf16 = 4 VGPRs
typedef __attribute__((ext_vector_type(4))) float f32x4;    // MFMA C/D frag

// tanh via exp pipe: tanh(x) = 1 - 2/(e^{2x}+1).  Handles +-inf correctly.
__device__ __forceinline__ float tanh_fast(float x) {
    float e = __expf(2.0f * x);
    return 1.0f - 2.0f * __builtin_amdgcn_rcpf(e + 1.0f);
}

union Pack8 { bf16x8 v; __hip_bfloat162 h[4]; };
__device__ __forceinline__ bf16x8 cvt8(float4 a, float4 b) {
    Pack8 p;
    p.h[0] = __float22bfloat162_rn(make_float2(a.x, a.y));
    p.h[1] = __float22bfloat162_rn(make_float2(a.z, a.w));
    p.h[2] = __float22bfloat162_rn(make_float2(b.x, b.y));
    p.h[3] = __float22bfloat162_rn(make_float2(b.z, b.w));
    return p.v;
}

// async global->LDS DMA, 16 B per lane. gptr is per-lane; lds dest is
// wave-uniform base + lane*16 (hardware rule — layout must be lane-ordered).
__device__ __forceinline__ void gl_lds16(const void* g, void* l) {
    __builtin_amdgcn_global_load_lds(
        (const __attribute__((address_space(1))) unsigned int*)g,
        (__attribute__((address_space(3))) unsigned int*)l, 16, 0, 0);
}

// ---------------- prep: zero/wq/mask-probe/cvtB in ONE launch --------------
// blk 0..255: zero scores/out/cnt/denom + wq GEMV (4 lanes per output, K-split
// -> 32-iter chains instead of 128, shfl-reduced).  blk 256: mask dtype probe.
// blk 257..512: Ua_w fp32 -> bf16 into ws (B operand for the MFMA GEMM).
__global__ __launch_bounds__(256) void k_prep(const float* __restrict__ query,
                                              const float* __restrict__ Wa_w,
                                              const float* __restrict__ Wa_b,
                                              const unsigned int* __restrict__ maskw,
                                              const float* __restrict__ Ua_w,
                                              float* __restrict__ scores,
                                              float* __restrict__ wq,
                                              float* __restrict__ out,
                                              int* __restrict__ flag,
                                              int* __restrict__ cnt,
                                              float* __restrict__ denom,
                                              ushort* __restrict__ Ub16) {
    const int blk = blockIdx.x, t = threadIdx.x;
    if (blk < 256) {
        const int tid = blk * 256 + t;
        scores[tid] = 0.f;
        if (tid < 32768) out[tid] = 0.f;
        if (tid < 512) cnt[tid] = 0;
        if (tid < 32) denom[tid] = 0.f;
        // GEMV: output o = tid>>2, K-quarter sub = tid&3 (lanes 4k..4k+3
        // share one output -> in-wave shfl reduce).
        const int o = tid >> 2, sub = tid & 3;
        const int bq = o >> 9, m = o & 511;
        const float4* q = (const float4*)(query + (size_t)bq * D_ + sub * 128);
        const float4* w = (const float4*)(Wa_w + (size_t)m * D_ + sub * 128);
        float acc = 0.f;
#pragma unroll 8
        for (int i = 0; i < 32; ++i) {
            float4 qv = q[i], wv = w[i];
            acc = fmaf(qv.x, wv.x, acc);
            acc = fmaf(qv.y, wv.y, acc);
            acc = fmaf(qv.z, wv.z, acc);
            acc = fmaf(qv.w, wv.w, acc);
        }
        acc += __shfl_down(acc, 2, 64);
        acc += __shfl_down(acc, 1, 64);
        if (sub == 0) wq[o] = acc + Wa_b[m];
    } else if (blk == 256) {
        __shared__ int found;
        if (t == 0) found = 0;
        __syncthreads();
        int f = 0;
        for (int i = 0; i < 64; ++i)
            if (maskw[t * 64 + i] > 1u) f = 1;
        if (f) atomicOr(&found, 1);
        __syncthreads();
        if (t == 0) *flag = found;
    } else {
        const int i = ((blk - 257) * 256 + t) * 8;   // 256 blocks * 2048 = 512K
        float4 a = *(const float4*)(Ua_w + i);
        float4 b = *(const float4*)(Ua_w + i + 4);
        *(bf16x8*)(Ub16 + i) = cvt8(a, b);
    }
}

// ---------------- MFMA scores + fused softmax/context tail ----------
// C[s,m] = sum_k keys[b,s,k]*Ua_w[m,k].  Block 128s x 128m, BK=64,
// 4 waves 2x2, wave = 4x4 of 16x16x32 bf16 MFMA frags.
// A (fp32 keys): coalesced global->VGPR, cvt, ds_write_b128, double-buffered.
// B (bf16 Ub16): async global_load_lds, double-buffered, issued one kt ahead.
// LDS rows 128B unpadded (DMA lane-order rule); XOR chunk swizzle kills
// bank conflicts. XCD swizzle: the 4 m-sibling blocks of one s-chunk land
// on the same XCD so the 4x keys re-read is L2-served.
//
// NEW: split-K-style "last-arriver" tail. After the 4 siblings atomicAdd
// their score partials, the last one (per-chunk counter) computes the
// unnormalized softmax weights for its 128 rows (|score|<=55.5 -> no max
// subtraction), accumulates denom[b] and the unnormalized context partial
// sum_s exp(score)*keys[s,:] straight from the (L2-hot) keys chunk.
// This removes the old k_ctx kernel's full 268 MB HBM re-read of keys.
__global__ __launch_bounds__(256, 2) void k_scores(const float* __restrict__ keys,
                                                   const ushort* __restrict__ Ub16,
                                                   const float* __restrict__ Ua_b,
                                                   const float* __restrict__ Va_w,
                                                   const float* __restrict__ wq,
                                                   const void* __restrict__ mask,
                                                   const int* __restrict__ flag,
                                                   int* __restrict__ cnt,
                                                   float* __restrict__ denom,
                                                   float* __restrict__ scores,
                                                   float* __restrict__ out) {
    __shared__ __align__(16) unsigned char smem[65536];
    unsigned char* Abase = smem;           // 2 x 16384 B  (A tiles)
    unsigned char* Bbase = smem + 32768;   // 2 x 16384 B  (B tiles)

    const int h    = blockIdx.x;
    const int xcd  = h & 7, slot = h >> 3;
    const int mj   = slot & 3;
    const int grp  = xcd + 8 * (slot >> 2);      // 0..511 : (b, s-chunk) id
    const int b    = grp >> 4;
    const int s0   = (grp & 15) * 128;
    const int m0   = mj * 128;

    const int t = threadIdx.x;
    const int wave = t >> 6, lane = t & 63;
    const int q = lane >> 4, r = lane & 15;
    const int sw = (wave >> 1) * 64, mw = (wave & 1) * 64;

    // A staging ids: thread -> row (t>>3), k-octet (t&7); 4 passes of 32 rows.
    const int arow = t >> 3, akq = t & 7;
    const int apc  = akq ^ (arow & 7);           // XOR-swizzled chunk
    const float* Ag = keys + ((size_t)b * S_ + s0 + arow) * K2D + akq * 8;

    // B staging ids (DMA): wave w covers rows 32w..32w+31 in 4 instrs of 8 rows.
    const int brow_l = lane >> 3, bcl = lane & 7;
    const int bsrc_c = bcl ^ brow_l;             // source chunk for this lane
    const ushort* Bg = Ub16 + (size_t)(m0 + 32 * wave + brow_l) * K2D + bsrc_c * 8;

    f32x4 acc[4][4];
#pragma unroll
    for (int i = 0; i < 4; ++i)
#pragma unroll
        for (int j = 0; j < 4; ++j) acc[i][j] = (f32x4){0.f, 0.f, 0.f, 0.f};

    // ---- prologue: stage kt=0 into buffer 0 ----
    {
        float4 fa0[4], fa1[4];
#pragma unroll
        for (int p = 0; p < 4; ++p) {
            const float* g = Ag + (size_t)(p * 32) * K2D;
            fa0[p] = *(const float4*)g;
            fa1[p] = *(const float4*)(g + 4);
        }
#pragma unroll
        for (int p = 0; p < 4; ++p)
            gl_lds16(Bg + (size_t)(8 * p) * K2D,
                     Bbase + (32 * wave + 8 * p) * 128);
#pragma unroll
        for (int p = 0; p < 4; ++p)
            *(bf16x8*)(Abase + (arow + 32 * p) * 128 + apc * 16) =
                cvt8(fa0[p], fa1[p]);
        __syncthreads();
    }

    for (int kt = 0; kt < 16; ++kt) {
        const int cur = kt & 1, nxt = cur ^ 1;
        unsigned char* Acur = Abase + cur * 16384;
        unsigned char* Bcur = Bbase + cur * 16384;

        float4 fa0[4], fa1[4];
        if (kt < 15) {
            const int ko = (kt + 1) * 64;
#pragma unroll
            for (int p = 0; p < 4; ++p) {
                const float* g = Ag + (size_t)(p * 32) * K2D + ko;
                fa0[p] = *(const float4*)g;
                fa1[p] = *(const float4*)(g + 4);
            }
#pragma unroll
            for (int p = 0; p < 4; ++p)
                gl_lds16(Bg + (size_t)(8 * p) * K2D + ko,
                         Bbase + nxt * 16384 + (32 * wave + 8 * p) * 128);
        }

        // ---- compute on current buffers ----
#pragma unroll
        for (int ks = 0; ks < 2; ++ks) {
            bf16x8 af[4], bf[4];
            const int lc = ks * 4 + q;           // logical 16B chunk in row
            const int pco = ((lc ^ (r & 7)) * 16);
#pragma unroll
            for (int i = 0; i < 4; ++i)
                af[i] = *(const bf16x8*)(Acur + (sw + i * 16 + r) * 128 + pco);
#pragma unroll
            for (int j = 0; j < 4; ++j)
                bf[j] = *(const bf16x8*)(Bcur + (mw + j * 16 + r) * 128 + pco);
#pragma unroll
            for (int i = 0; i < 4; ++i)
#pragma unroll
                for (int j = 0; j < 4; ++j)
                    acc[i][j] = __builtin_amdgcn_mfma_f32_16x16x32_bf16(
                        af[i], bf[j], acc[i][j], 0, 0, 0);
        }

        if (kt < 15) {
#pragma unroll
            for (int p = 0; p < 4; ++p)
                *(bf16x8*)(Abase + nxt * 16384 + (arow + 32 * p) * 128 + apc * 16) =
                    cvt8(fa0[p], fa1[p]);
        }
        __syncthreads();
    }

    // Epilogue. C/D layout: col(m)=lane&15, row(s)=q*4+reg.
    float vaw[4], wqb[4];
#pragma unroll
    for (int j = 0; j < 4; ++j) {
        int m = m0 + mw + 16 * j + r;
        vaw[j] = Va_w[m];
        wqb[j] = wq[b * M_ + m] + Ua_b[m];
    }
    float* red = (float*)smem;           // overlay: 128 x 33 floats = 16.9 KB
    const int col = (wave & 1) * 16 + r;
#pragma unroll
    for (int i = 0; i < 4; ++i) {
#pragma unroll
        for (int rg = 0; rg < 4; ++rg) {
            int sl = sw + 16 * i + 4 * q + rg;
            float p = 0.f;
#pragma unroll
            for (int j = 0; j < 4; ++j)
                p += vaw[j] * tanh_fast(acc[i][j][rg] + wqb[j]);
            red[sl * 33 + col] = p;    // every (sl,col) written exactly once
        }
    }
    __syncthreads();
    if (t < 128) {
        float sum = 0.f;
#pragma unroll
        for (int c = 0; c < 32; ++c) sum += red[t * 33 + c];
        atomicAdd(&scores[(size_t)b * S_ + s0 + t], sum);
    }
    // __syncthreads drains each thread's atomic (vmcnt(0) before s_barrier),
    // so after it ALL of this block's score-adds are at the L2 coherence point.
    __syncthreads();
    int* lflag = (int*)(smem + 22528);
    if (t == 0) {
        __threadfence();                         // release before semaphore
        *lflag = (atomicAdd(&cnt[grp], 1) == 3); // last of 4 m-siblings?
    }
    __syncthreads();
    if (!*lflag) return;

    // ---- last sibling: fused softmax weights + context partial ----
    __threadfence();   // acquire: invalidate L1 so scores reads see final L2
    float* wbuf = (float*)(smem + 20480);        // 128 floats
    const bool bytemode = (*flag) != 0;
    if (t < 128) {
        const size_t idx = (size_t)b * S_ + s0 + t;
        const bool msk = bytemode
            ? (((const unsigned char*)mask)[idx] != 0)
            : (((const int*)mask)[idx] != 0);
        // |score| <= sum|Va_w| ~ 55.5 < 88 => exp never overflows; no max sub.
        wbuf[t] = msk ? 0.f : expf(scores[idx]);
    }
    __syncthreads();
    if (t < 64) {
        float s2 = wbuf[t] + wbuf[t + 64];
#pragma unroll
        for (int off = 32; off > 0; off >>= 1) s2 += __shfl_down(s2, off, 64);
        if (t == 0) atomicAdd(&denom[b], s2);
    }
    // context partial: thread t owns columns 4t..4t+3 over the 128 rows.
    // keys chunk (512 KB) was just streamed by the 4 siblings on this XCD
    // -> L2-hot; worst case L3 (keys ~fits in 256 MB Infinity Cache).
    const float4* kp = (const float4*)(keys + ((size_t)b * S_ + s0) * K2D);
    float4 a2 = {0.f, 0.f, 0.f, 0.f};
#pragma unroll 8
    for (int s = 0; s < 128; ++s) {
        const float w2 = wbuf[s];
        const float4 kv = kp[(size_t)s * 256 + t];
        a2.x = fmaf(w2, kv.x, a2.x);
        a2.y = fmaf(w2, kv.y, a2.y);
        a2.z = fmaf(w2, kv.z, a2.z);
        a2.w = fmaf(w2, kv.w, a2.w);
    }
    atomicAdd(&out[b * 1024 + t * 4 + 0], a2.x);
    atomicAdd(&out[b * 1024 + t * 4 + 1], a2.y);
    atomicAdd(&out[b * 1024 + t * 4 + 2], a2.z);
    atomicAdd(&out[b * 1024 + t * 4 + 3], a2.w);
}

// ---------------- normalize: out /= denom[b] ----------------
__global__ __launch_bounds__(256) void k_norm(float* __restrict__ out,
                                              const float* __restrict__ denom) {
    const int b = blockIdx.x, t = threadIdx.x;
    const float inv = 1.0f / denom[b];
    float4* o = (float4*)(out + (size_t)b * 1024);
    float4 v = o[t];
    v.x *= inv; v.y *= inv; v.z *= inv; v.w *= inv;
    o[t] = v;
}

extern "C" void kernel_launch(void* const* d_in, const int* in_sizes, int n_in,
                              void* d_out, int out_size, void* d_ws, size_t ws_size,
                              hipStream_t stream) {
    const float* query = (const float*)d_in[0];
    const float* keys  = (const float*)d_in[1];
    const void*  mask  = d_in[2];
    const float* Wa_w  = (const float*)d_in[3];
    const float* Wa_b  = (const float*)d_in[4];
    const float* Ua_w  = (const float*)d_in[5];
    const float* Ua_b  = (const float*)d_in[6];
    const float* Va_w  = (const float*)d_in[7];
    // Va_b is softmax-invariant -> dropped.

    float*  wsf    = (float*)d_ws;
    float*  scores = wsf + WS_SCORES;
    float*  wq     = wsf + WS_WQ;
    int*    flag   = (int*)(wsf + WS_FLAG);
    float*  denom  = wsf + WS_DENOM;
    int*    cnt    = (int*)(wsf + WS_CNT);
    ushort* Ub16   = (ushort*)(wsf + WS_UAB16);
    float*  out    = (float*)d_out;

    k_prep<<<513, 256, 0, stream>>>(query, Wa_w, Wa_b,
                                    (const unsigned int*)mask, Ua_w,
                                    scores, wq, out, flag, cnt, denom, Ub16);
    k_scores<<<2048, 256, 0, stream>>>(keys, Ub16, Ua_b, Va_w, wq,
                                       mask, flag, cnt, denom, scores, out);
    k_norm<<<32, 256, 0, stream>>>(out, denom);
}

// Round 2
// 457.032 us; speedup vs baseline: 1.4643x; 1.4643x over previous
//
#include <hip/hip_runtime.h>
#include <hip/hip_bf16.h>
#include <cstdint>
#include <cstddef>

// Problem constants (BahdanauAttention): B=32, S=2048, d=512, M=512, K=2d=1024
#define B_   32
#define S_   2048
#define D_   512
#define K2D  1024
#define M_   512

// ws layout (float indices). Total = 66048 B + 1 MB ~= 1.07 MB (< 1.64 MB proven).
#define WS_WQ     0        // [B][M] = 16384 floats
#define WS_FLAG   16384    // 1 int
#define WS_DENOM  16448    // 32 floats
#define WS_UAB16  16512    // 512*1024 bf16 = 1 MB (byte off 66048, 16B aligned)

typedef __attribute__((ext_vector_type(8))) short bf16x8;   // 8 bf16 = 4 VGPRs
typedef __attribute__((ext_vector_type(4))) float f32x4;    // MFMA C/D frag

// tanh via exp pipe: tanh(x) = 1 - 2/(e^{2x}+1).  Handles +-inf correctly.
__device__ __forceinline__ float tanh_fast(float x) {
    float e = __expf(2.0f * x);
    return 1.0f - 2.0f * __builtin_amdgcn_rcpf(e + 1.0f);
}

union Pack8 { bf16x8 v; __hip_bfloat162 h[4]; };
__device__ __forceinline__ bf16x8 cvt8(float4 a, float4 b) {
    Pack8 p;
    p.h[0] = __float22bfloat162_rn(make_float2(a.x, a.y));
    p.h[1] = __float22bfloat162_rn(make_float2(a.z, a.w));
    p.h[2] = __float22bfloat162_rn(make_float2(b.x, b.y));
    p.h[3] = __float22bfloat162_rn(make_float2(b.z, b.w));
    return p.v;
}

// async global->LDS DMA, 16 B per lane. gptr is per-lane; lds dest is
// wave-uniform base + lane*16 (hardware rule — layout must be lane-ordered).
__device__ __forceinline__ void gl_lds16(const void* g, void* l) {
    __builtin_amdgcn_global_load_lds(
        (const __attribute__((address_space(1))) unsigned int*)g,
        (__attribute__((address_space(3))) unsigned int*)l, 16, 0, 0);
}

// ---------------- prep: zero/wq/mask-probe/cvtB in ONE launch --------------
// blk 0..255: zero out/denom + wq GEMV (4 lanes per output, K-split, shfl-red).
// blk 256: mask dtype probe (coalesced, 2048 words — byte-mode false-negative
//          prob = (1/8)^2048 ~ 0).  blk 257..512: Ua_w fp32 -> bf16.
__global__ __launch_bounds__(256) void k_prep(const float* __restrict__ query,
                                              const float* __restrict__ Wa_w,
                                              const float* __restrict__ Wa_b,
                                              const unsigned int* __restrict__ maskw,
                                              const float* __restrict__ Ua_w,
                                              float* __restrict__ wq,
                                              float* __restrict__ out,
                                              int* __restrict__ flag,
                                              float* __restrict__ denom,
                                              ushort* __restrict__ Ub16) {
    const int blk = blockIdx.x, t = threadIdx.x;
    if (blk < 256) {
        const int tid = blk * 256 + t;
        if (tid < 32768) out[tid] = 0.f;
        if (tid < 32) denom[tid] = 0.f;
        // GEMV: output o = tid>>2, K-quarter sub = tid&3.
        const int o = tid >> 2, sub = tid & 3;
        const int bq = o >> 9, m = o & 511;
        const float4* q = (const float4*)(query + (size_t)bq * D_ + sub * 128);
        const float4* w = (const float4*)(Wa_w + (size_t)m * D_ + sub * 128);
        float acc = 0.f;
#pragma unroll 8
        for (int i = 0; i < 32; ++i) {
            float4 qv = q[i], wv = w[i];
            acc = fmaf(qv.x, wv.x, acc);
            acc = fmaf(qv.y, wv.y, acc);
            acc = fmaf(qv.z, wv.z, acc);
            acc = fmaf(qv.w, wv.w, acc);
        }
        acc += __shfl_down(acc, 2, 64);
        acc += __shfl_down(acc, 1, 64);
        if (sub == 0) wq[o] = acc + Wa_b[m];
    } else if (blk == 256) {
        __shared__ int found;
        if (t == 0) found = 0;
        __syncthreads();
        int f = 0;
#pragma unroll
        for (int i = 0; i < 8; ++i)
            if (maskw[i * 256 + t] > 1u) f = 1;
        if (f) atomicOr(&found, 1);
        __syncthreads();
        if (t == 0) *flag = found;
    } else {
        const int i = ((blk - 257) * 256 + t) * 8;   // 256 blocks * 2048 = 512K
        float4 a = *(const float4*)(Ua_w + i);
        float4 b = *(const float4*)(Ua_w + i + 4);
        *(bf16x8*)(Ub16 + i) = cvt8(a, b);
    }
}

// ---------------- fused scores + softmax + context ----------------
// One block per (b, s-chunk of 128): computes C[s, 0..511] for ALL of M, so the
// full score row finishes locally — no cross-block semaphore, no scores array.
// Tile 128s x 512m, BK=64, 8 waves (2s x 4m), per wave acc[4][8] of 16x16x32.
// LDS: A 2x16KB (keys fp32->bf16 reg-staged) + B 2x64KB (Ub16 via DMA) = 160KB
// exactly -> 1 block/CU, 8 waves (2/SIMD) — same wave count as the old 128x128
// kernel but 2x the MFMA per barrier. B (1 MB total) is shared by ALL blocks ->
// L2/L3-served after first touch per XCD.
// Tail (per block, no semaphore): tanh/Va reduce -> exp -> denom atomicAdd +
// unnormalized context partial from a fp32 keys re-read (spread across block
// lifetimes -> overlaps other blocks' GEMM, unlike R1's clustered tails).
__global__ __launch_bounds__(512, 2) void k_main(const float* __restrict__ keys,
                                                 const ushort* __restrict__ Ub16,
                                                 const float* __restrict__ Ua_b,
                                                 const float* __restrict__ Va_w,
                                                 const float* __restrict__ wq,
                                                 const void* __restrict__ mask,
                                                 const int* __restrict__ flag,
                                                 float* __restrict__ denom,
                                                 float* __restrict__ out) {
    __shared__ __align__(16) unsigned char smem[163840];
    unsigned char* Abase = smem;            // 2 x 16384 B
    unsigned char* Bbase = smem + 32768;    // 2 x 65536 B

    const int grp = blockIdx.x;             // 0..511 : (b, s-chunk)
    const int b   = grp >> 4;
    const int s0  = (grp & 15) * 128;

    const int t = threadIdx.x;
    const int wave = t >> 6, lane = t & 63;
    const int q = lane >> 4, r = lane & 15;
    const int sw = (wave >> 2) * 64;        // s-group: waves 0-3 / 4-7
    const int mw = (wave & 3) * 128;        // m-group: 4 panels of 128

    // A staging: thread -> row t>>2 (0..127), chunks 2*(t&3), +1. Reg-staged
    // (fp32->bf16 cvt), XOR chunk swizzle on the WRITE side.
    const int arow = t >> 2, ac = (t & 3) * 2;
    const float* Ag = keys + ((size_t)(b * S_ + s0 + arow)) * K2D + ac * 8;
    const int ad0 = arow * 128 + ((ac ^ (arow & 7)) * 16);
    const int ad1 = arow * 128 + (((ac + 1) ^ (arow & 7)) * 16);

    // B staging (DMA, lane-ordered dest): wave w covers rows 64w..64w+63 in 8
    // instrs of 8 rows; XOR swizzle folded into the per-lane SOURCE address.
    const int brl = lane >> 3, bcl = lane & 7;
    const ushort* Bg = Ub16 + (size_t)(64 * wave + brl) * K2D + (bcl ^ brl) * 8;

    f32x4 acc[4][8];
#pragma unroll
    for (int i = 0; i < 4; ++i)
#pragma unroll
        for (int j = 0; j < 8; ++j) acc[i][j] = (f32x4){0.f, 0.f, 0.f, 0.f};

    // ---- prologue: stage kt=0 into buffer 0 ----
    {
        const float4* g = (const float4*)Ag;
        float4 f0 = g[0], f1 = g[1], f2 = g[2], f3 = g[3];
#pragma unroll
        for (int p = 0; p < 8; ++p)
            gl_lds16(Bg + (size_t)(8 * p) * K2D,
                     Bbase + (64 * wave + 8 * p) * 128);
        *(bf16x8*)(Abase + ad0) = cvt8(f0, f1);
        *(bf16x8*)(Abase + ad1) = cvt8(f2, f3);
        __syncthreads();
    }

    for (int kt = 0; kt < 16; ++kt) {
        const int cur = kt & 1, nxt = cur ^ 1;
        unsigned char* Acur = Abase + cur * 16384;
        unsigned char* Bcur = Bbase + cur * 65536;

        float4 f0, f1, f2, f3;
        if (kt < 15) {
            const int ko = (kt + 1) * 64;
            const float4* g = (const float4*)(Ag + ko);
            f0 = g[0]; f1 = g[1]; f2 = g[2]; f3 = g[3];
#pragma unroll
            for (int p = 0; p < 8; ++p)
                gl_lds16(Bg + (size_t)(8 * p) * K2D + ko,
                         Bbase + nxt * 65536 + (64 * wave + 8 * p) * 128);
        }

        // ---- compute on current buffers: 2 ks x 32 MFMA per wave ----
#pragma unroll
        for (int ks = 0; ks < 2; ++ks) {
            bf16x8 af[4], bf[8];
            const int lc = ks * 4 + q;
            const int pco = ((lc ^ (r & 7)) * 16);
#pragma unroll
            for (int i = 0; i < 4; ++i)
                af[i] = *(const bf16x8*)(Acur + (sw + i * 16 + r) * 128 + pco);
#pragma unroll
            for (int j = 0; j < 8; ++j)
                bf[j] = *(const bf16x8*)(Bcur + (mw + j * 16 + r) * 128 + pco);
#pragma unroll
            for (int i = 0; i < 4; ++i)
#pragma unroll
                for (int j = 0; j < 8; ++j)
                    acc[i][j] = __builtin_amdgcn_mfma_f32_16x16x32_bf16(
                        af[i], bf[j], acc[i][j], 0, 0, 0);
        }

        if (kt < 15) {
            unsigned char* An = Abase + nxt * 16384;
            *(bf16x8*)(An + ad0) = cvt8(f0, f1);
            *(bf16x8*)(An + ad1) = cvt8(f2, f3);
        }
        __syncthreads();
    }

    // ---- epilogue: tanh + Va reduce over all 512 m (in-block) ----
    // C/D layout: col(m)=lane&15, row(s)=q*4+reg.
    float vaw[8], wqb[8];
#pragma unroll
    for (int j = 0; j < 8; ++j) {
        int m = mw + 16 * j + r;
        vaw[j] = Va_w[m];
        wqb[j] = wq[b * M_ + m] + Ua_b[m];
    }
    float* red = (float*)smem;              // overlay: 128 x 65 floats = 33.3 KB
    const int col = (wave & 3) * 16 + r;
#pragma unroll
    for (int i = 0; i < 4; ++i) {
#pragma unroll
        for (int rg = 0; rg < 4; ++rg) {
            int sl = sw + 16 * i + 4 * q + rg;
            float p = 0.f;
#pragma unroll
            for (int j = 0; j < 8; ++j)
                p += vaw[j] * tanh_fast(acc[i][j][rg] + wqb[j]);
            red[sl * 65 + col] = p;         // every (sl,col) written exactly once
        }
    }
    __syncthreads();

    float* wbuf = (float*)(smem + 33280);   // 128 floats, after red
    const bool bytemode = (*flag) != 0;
    if (t < 128) {
        float sum = 0.f;
#pragma unroll
        for (int c = 0; c < 64; ++c) sum += red[t * 65 + c];
        const size_t idx = (size_t)b * S_ + s0 + t;
        const bool msk = bytemode
            ? (((const unsigned char*)mask)[idx] != 0)
            : (((const int*)mask)[idx] != 0);
        // |score| <= sum|Va_w| ~ 55.5 < 88 => exp never overflows; no max sub.
        wbuf[t] = msk ? 0.f : expf(sum);
    }
    __syncthreads();

    if (t < 64) {
        float s2 = wbuf[t] + wbuf[t + 64];
#pragma unroll
        for (int off = 32; off > 0; off >>= 1) s2 += __shfl_down(s2, off, 64);
        if (t == 0) atomicAdd(&denom[b], s2);
    }

    // context partial: thread t owns cols 2t..2t+1 over the 128 rows (fp32
    // keys re-read; wave reads 512 B contiguous per row-step — coalesced).
    const float2* kp = (const float2*)(keys + ((size_t)b * S_ + s0) * K2D);
    float2 a2 = {0.f, 0.f};
#pragma unroll 8
    for (int s = 0; s < 128; ++s) {
        const float w2 = wbuf[s];
        const float2 kv = kp[(size_t)s * 512 + t];
        a2.x = fmaf(w2, kv.x, a2.x);
        a2.y = fmaf(w2, kv.y, a2.y);
    }
    atomicAdd(&out[b * 1024 + 2 * t + 0], a2.x);
    atomicAdd(&out[b * 1024 + 2 * t + 1], a2.y);
}

// ---------------- normalize: out /= denom[b] ----------------
__global__ __launch_bounds__(256) void k_norm(float* __restrict__ out,
                                              const float* __restrict__ denom) {
    const int b = blockIdx.x, t = threadIdx.x;
    const float inv = 1.0f / denom[b];
    float4* o = (float4*)(out + (size_t)b * 1024);
    float4 v = o[t];
    v.x *= inv; v.y *= inv; v.z *= inv; v.w *= inv;
    o[t] = v;
}

extern "C" void kernel_launch(void* const* d_in, const int* in_sizes, int n_in,
                              void* d_out, int out_size, void* d_ws, size_t ws_size,
                              hipStream_t stream) {
    const float* query = (const float*)d_in[0];
    const float* keys  = (const float*)d_in[1];
    const void*  mask  = d_in[2];
    const float* Wa_w  = (const float*)d_in[3];
    const float* Wa_b  = (const float*)d_in[4];
    const float* Ua_w  = (const float*)d_in[5];
    const float* Ua_b  = (const float*)d_in[6];
    const float* Va_w  = (const float*)d_in[7];
    // Va_b is softmax-invariant -> dropped.

    float*  wsf    = (float*)d_ws;
    float*  wq     = wsf + WS_WQ;
    int*    flag   = (int*)(wsf + WS_FLAG);
    float*  denom  = wsf + WS_DENOM;
    ushort* Ub16   = (ushort*)(wsf + WS_UAB16);
    float*  out    = (float*)d_out;

    k_prep<<<513, 256, 0, stream>>>(query, Wa_w, Wa_b,
                                    (const unsigned int*)mask, Ua_w,
                                    wq, out, flag, denom, Ub16);
    k_main<<<512, 512, 0, stream>>>(keys, Ub16, Ua_b, Va_w, wq,
                                    mask, flag, denom, out);
    k_norm<<<32, 256, 0, stream>>>(out, denom);
}